// Round 1
// baseline (13491.196 us; speedup 1.0000x reference)
//
#include <hip/hip_runtime.h>
#include <hip/hip_bf16.h>

#define DT 0.01f

// ---------- helpers ----------
static __device__ __forceinline__ unsigned short f2bf(float f) {
    unsigned int u = __float_as_uint(f);
    u += 0x7fffu + ((u >> 16) & 1u);   // round-to-nearest-even
    return (unsigned short)(u >> 16);
}

// dot of 8 bf16 weights (packed in uint4) with 8 fp32 activations
static __device__ __forceinline__ float dot8(uint4 u, float4 a, float4 b) {
    float s;
    s  = __uint_as_float(u.x << 16)          * a.x;
    s += __uint_as_float(u.x & 0xffff0000u)  * a.y;
    s += __uint_as_float(u.y << 16)          * a.z;
    s += __uint_as_float(u.y & 0xffff0000u)  * a.w;
    s += __uint_as_float(u.z << 16)          * b.x;
    s += __uint_as_float(u.z & 0xffff0000u)  * b.y;
    s += __uint_as_float(u.w << 16)          * b.z;
    s += __uint_as_float(u.w & 0xffff0000u)  * b.w;
    return s;
}

// ---------- kernel 1: pack h2h into two bf16 layouts ----------
// wp1[(i8*512 + j)*8 + e] = bf16( w[(i8*8+e)*512 + j] )   pass1: z_j = sum_i hy[i] w[i][j]
// wp2[(i8*512 + j)*8 + e] = bf16( w[j*512 + (i8*8+e)] )   pass2: rec_j = sum_i s[i] w[j][i]
__global__ __launch_bounds__(256) void prep_weights(const float* __restrict__ w,
                                                    unsigned short* __restrict__ wp1,
                                                    unsigned short* __restrict__ wp2) {
    int idx = blockIdx.x * blockDim.x + threadIdx.x;   // 0 .. 32767
    if (idx >= 64 * 512) return;
    int i8 = idx >> 9;     // 0..63
    int j  = idx & 511;
    size_t base = (size_t)(i8 * 512 + j) * 8;
    #pragma unroll
    for (int e = 0; e < 8; ++e) {
        int i = i8 * 8 + e;
        wp1[base + e] = f2bf(w[(size_t)i * 512 + j]);
        wp2[base + e] = f2bf(w[(size_t)j * 512 + i]);
    }
}

// ---------- kernel 2: i2h = tanh(x @ x2h), written into d_out's all_states slots ----------
// x: [B*T, 64], x2h: [64, 512], out: [B*T, 512] fp32
__global__ __launch_bounds__(512) void i2h_kernel(const float* __restrict__ x,
                                                  const float* __restrict__ x2h,
                                                  float* __restrict__ out) {
    __shared__ __align__(16) float xs[16 * 64];
    int bt0 = blockIdx.x * 16;
    int tid = threadIdx.x;
    xs[tid]       = x[(size_t)bt0 * 64 + tid];
    xs[tid + 512] = x[(size_t)bt0 * 64 + tid + 512];
    __syncthreads();

    float acc[16];
    #pragma unroll
    for (int r = 0; r < 16; ++r) acc[r] = 0.f;

    for (int i4 = 0; i4 < 16; ++i4) {
        float w0 = x2h[(i4 * 4 + 0) * 512 + tid];
        float w1 = x2h[(i4 * 4 + 1) * 512 + tid];
        float w2 = x2h[(i4 * 4 + 2) * 512 + tid];
        float w3 = x2h[(i4 * 4 + 3) * 512 + tid];
        #pragma unroll
        for (int r = 0; r < 16; ++r) {
            float4 xv = *(const float4*)&xs[r * 64 + i4 * 4];
            acc[r] += xv.x * w0 + xv.y * w1 + xv.z * w2 + xv.w * w3;
        }
    }
    #pragma unroll
    for (int r = 0; r < 16; ++r)
        out[(size_t)(bt0 + r) * 512 + tid] = tanhf(acc[r]);
}

// ---------- kernel 3: the recurrence, one workgroup per batch row ----------
// out initially holds i2h (fp32); each step reads i2h[b,t,:] then overwrites with hy.
__global__ __launch_bounds__(512) void recur_kernel(const uint4* __restrict__ wp1,
                                                    const uint4* __restrict__ wp2,
                                                    const float* __restrict__ bias,
                                                    float* __restrict__ out) {
    __shared__ __align__(16) float hyS[512];
    __shared__ __align__(16) float sS[512];
    const int b = blockIdx.x;
    const int j = threadIdx.x;

    float hy = 0.f, hz = 0.f;
    const float bj = bias[j];
    hyS[j] = 0.f;
    __syncthreads();

    float* outb = out + (size_t)b * 1024 * 512;

    for (int t = 0; t < 1024; ++t) {
        // ---- pass 1: z_j = bias_j + sum_i hy[i] * w[i][j] ----
        float z0 = bj, z1 = 0.f;
        #pragma unroll 8
        for (int i8 = 0; i8 < 64; i8 += 2) {
            uint4 u0 = wp1[(i8 << 9) + j];
            uint4 u1 = wp1[((i8 + 1) << 9) + j];
            const float4* h4 = (const float4*)(hyS + (i8 << 3));
            z0 += dot8(u0, h4[0], h4[1]);
            z1 += dot8(u1, h4[2], h4[3]);
        }
        float s = tanhf(z0 + z1);
        sS[j] = s;
        __syncthreads();   // hyS reads done; sS visible

        // ---- pass 2: rec_j = sum_i s[i] * w[j][i] ----
        float r0 = 0.f, r1 = 0.f;
        #pragma unroll 8
        for (int i8 = 0; i8 < 64; i8 += 2) {
            uint4 u0 = wp2[(i8 << 9) + j];
            uint4 u1 = wp2[((i8 + 1) << 9) + j];
            const float4* s4 = (const float4*)(sS + (i8 << 3));
            r0 += dot8(u0, s4[0], s4[1]);
            r1 += dot8(u1, s4[2], s4[3]);
        }
        float rec = r0 + r1;

        // ---- pointwise update (GAMMA=1, EPSILON=1, DT=0.01) ----
        float i2h = outb[(size_t)t * 512 + j];
        hz = hz + DT * (i2h - rec - hy - hz);
        hy = hy + DT * hz;
        outb[(size_t)t * 512 + j] = hy;
        hyS[j] = hy;
        __syncthreads();   // sS reads done; hyS visible for next step
    }

    // hy_f output (concatenated after all_states)
    out[(size_t)128 * 1024 * 512 + (size_t)b * 512 + j] = hy;
}

// ---------- launch ----------
extern "C" void kernel_launch(void* const* d_in, const int* in_sizes, int n_in,
                              void* d_out, int out_size, void* d_ws, size_t ws_size,
                              hipStream_t stream) {
    const float* x    = (const float*)d_in[0];   // [128,1024,64]
    const float* x2h  = (const float*)d_in[1];   // [64,512]
    const float* h2h  = (const float*)d_in[2];   // [512,512]
    const float* bias = (const float*)d_in[3];   // [512]
    float* out = (float*)d_out;

    unsigned short* wp1 = (unsigned short*)d_ws;           // 512 KB
    unsigned short* wp2 = wp1 + 512 * 512;                 // 512 KB

    prep_weights<<<128, 256, 0, stream>>>(h2h, wp1, wp2);
    i2h_kernel<<<8192, 512, 0, stream>>>(x, x2h, out);
    recur_kernel<<<128, 512, 0, stream>>>((const uint4*)wp1, (const uint4*)wp2, bias, out);
}

// Round 2
// 9598.946 us; speedup vs baseline: 1.4055x; 1.4055x over previous
//
#include <hip/hip_runtime.h>

#define DT 0.01f
#define NH 512
#define T_STEPS 1024
#define NB 128
#define SLICE 64
#define NGROUPS 32

typedef _Float16 h2v __attribute__((ext_vector_type(2)));
typedef _Float16 h8v __attribute__((ext_vector_type(8)));

#if defined(__has_builtin)
#if __has_builtin(__builtin_amdgcn_fdot2)
#define HAVE_FDOT2 1
#endif
#endif

#ifdef HAVE_FDOT2
#define FDOT2(a, b, c) __builtin_amdgcn_fdot2((a), (b), (c), false)
#else
static __device__ __forceinline__ float FDOT2(h2v a, h2v b, float c) {
    return c + (float)a[0] * (float)b[0] + (float)a[1] * (float)b[1];
}
#endif

// LDS layout (bytes)
#define O_W1 0        // [64 i8][64 jj] h8v  = 64 KB   w1p: w[i8*8+e][jm+jj]
#define O_W2 65536    // [64 i8][64 jj] h8v  = 64 KB   w2p: w[jm+jj][i8*8+e]
#define O_HY 131072   // [4][512] fp16       = 4 KB
#define O_S  135168   // [4][512] fp16       = 4 KB
#define O_Z  139264   // [8 q][64 jj][4 r] f32 = 8 KB
#define O_STG 147456  // [4 r][64 jj] fp16   = 512 B
#define LDS_BYTES 147968

// ---------- kernel 1: i2h = tanh(x @ x2h) -> written into d_out all_states slots ----------
__global__ __launch_bounds__(512) void i2h_kernel(const float* __restrict__ x,
                                                  const float* __restrict__ x2h,
                                                  float* __restrict__ out) {
    __shared__ __align__(16) float xs[16 * 64];
    int bt0 = blockIdx.x * 16;
    int tid = threadIdx.x;
    xs[tid]       = x[(size_t)bt0 * 64 + tid];
    xs[tid + 512] = x[(size_t)bt0 * 64 + tid + 512];
    __syncthreads();

    float acc[16];
    #pragma unroll
    for (int r = 0; r < 16; ++r) acc[r] = 0.f;

    for (int i4 = 0; i4 < 16; ++i4) {
        float w0 = x2h[(i4 * 4 + 0) * 512 + tid];
        float w1 = x2h[(i4 * 4 + 1) * 512 + tid];
        float w2 = x2h[(i4 * 4 + 2) * 512 + tid];
        float w3 = x2h[(i4 * 4 + 3) * 512 + tid];
        #pragma unroll
        for (int r = 0; r < 16; ++r) {
            float4 xv = *(const float4*)&xs[r * 64 + i4 * 4];
            acc[r] += xv.x * w0 + xv.y * w1 + xv.z * w2 + xv.w * w3;
        }
    }
    #pragma unroll
    for (int r = 0; r < 16; ++r)
        out[(size_t)(bt0 + r) * 512 + tid] = tanhf(acc[r]);
}

// ---------- kernel 2: recurrence. 256 WGs, group = 8 WGs x 4 batch rows, LDS-resident weights ----------
__global__ __launch_bounds__(512, 1) void recur2(const float* __restrict__ h2h,
                                                 const float* __restrict__ bias,
                                                 float* __restrict__ out,
                                                 unsigned long long* __restrict__ HYx,
                                                 unsigned long long* __restrict__ Sx,
                                                 unsigned int* __restrict__ flags) {
    extern __shared__ unsigned char lds[];
    h8v* w1p       = (h8v*)(lds + O_W1);
    h8v* w2p       = (h8v*)(lds + O_W2);
    _Float16* hyH  = (_Float16*)(lds + O_HY);
    _Float16* sH   = (_Float16*)(lds + O_S);
    float* zred    = (float*)(lds + O_Z);
    _Float16* stg  = (_Float16*)(lds + O_STG);

    const int tid = threadIdx.x;
    const int G   = blockIdx.x >> 3;   // group (4 batch rows)
    const int m   = blockIdx.x & 7;    // member (64-col slice)
    const int jj  = tid & 63;
    const int q   = tid >> 6;          // i-octant / wave id
    const int jm  = m * SLICE;

    // ---- one-time: load + fp16-convert weight slices into LDS ----
    for (int it = 0; it < 8; ++it) {
        int gidx = it * 512 + tid;
        int i8 = gidx >> 6, j = gidx & 63;          // lanes run over j -> coalesced
        h8v wv;
        #pragma unroll
        for (int e = 0; e < 8; ++e)
            wv[e] = (_Float16)h2h[(size_t)(i8 * 8 + e) * NH + jm + j];
        w1p[i8 * 64 + j] = wv;
    }
    for (int it = 0; it < 8; ++it) {
        int gidx = it * 512 + tid;
        int j = gidx >> 6, i8 = gidx & 63;          // lanes run over i8 -> coalesced rows
        const float* rp = h2h + (size_t)(jm + j) * NH + i8 * 8;
        h8v wv;
        #pragma unroll
        for (int e = 0; e < 8; ++e) wv[e] = (_Float16)rp[e];
        w2p[i8 * 64 + j] = wv;
    }

    unsigned long long* HYg = HYx + (size_t)G * 512;   // [8 m][4 r][64 jj] fp16 = 512 u64
    unsigned long long* Sg  = Sx  + (size_t)G * 512;
    unsigned int* flag = flags + G * 32;               // one counter / group, padded line

    // unpack mapping for exchange reads: u64 tid covers fp16 elems (m,r,jj0..jj0+3)
    const int um = tid >> 6;
    const int ur = (tid >> 4) & 3;
    const int uj = (tid & 15) * 4;
    const int uoff = ur * NH + um * 64 + uj;

    const bool owner = (q < 4);
    const int r = q;
    float hy = 0.f, hz = 0.f;
    float bj = 0.f;
    const float* inRow = nullptr;
    float* outRow = nullptr;
    if (owner) {
        bj = bias[jm + jj];
        outRow = out + ((size_t)(4 * G + r) * T_STEPS) * NH + jm + jj;
        inRow = outRow;
    }

    __syncthreads();   // weights ready

    unsigned int arrive = 0;

    for (int t = 0; t < T_STEPS; ++t) {
        // A: fetch full HY (zeros at t=0 via memset) from coherence point -> LDS
        unsigned long long hv =
            __hip_atomic_load(HYg + tid, __ATOMIC_RELAXED, __HIP_MEMORY_SCOPE_AGENT);
        float iv = 0.f;
        if (owner) iv = inRow[(size_t)t * NH];   // i2h prefetch (slot not yet overwritten)
        *(unsigned long long*)(hyH + uoff) = hv;
        __syncthreads();

        // B: pass 1 partials: z[r][jj] over i in [q*64, q*64+64)
        {
            float acc[4] = {0.f, 0.f, 0.f, 0.f};
            #pragma unroll
            for (int k = 0; k < 8; ++k) {
                const int i8 = q * 8 + k;
                h8v wv = w1p[i8 * 64 + jj];
                h2v wA = {wv[0], wv[1]}, wB = {wv[2], wv[3]},
                    wC = {wv[4], wv[5]}, wD = {wv[6], wv[7]};
                #pragma unroll
                for (int rr = 0; rr < 4; ++rr) {
                    h8v av = *(const h8v*)(hyH + rr * NH + i8 * 8);
                    h2v aA = {av[0], av[1]}, aB = {av[2], av[3]},
                        aC = {av[4], av[5]}, aD = {av[6], av[7]};
                    float a = acc[rr];
                    a = FDOT2(wA, aA, a); a = FDOT2(wB, aB, a);
                    a = FDOT2(wC, aC, a); a = FDOT2(wD, aD, a);
                    acc[rr] = a;
                }
            }
            *(float4*)(zred + (q * 64 + jj) * 4) = make_float4(acc[0], acc[1], acc[2], acc[3]);
        }
        __syncthreads();

        // owner: 8-way reduce + bias + tanh -> staging
        if (owner) {
            float z = bj;
            #pragma unroll
            for (int qq = 0; qq < 8; ++qq) z += zred[(qq * 64 + jj) * 4 + r];
            stg[r * 64 + jj] = (_Float16)tanhf(z);
        }
        __syncthreads();

        // push S slice (512 B) to coherence point
        if (tid < 64)
            __hip_atomic_store(Sg + m * 64 + tid, *(const unsigned long long*)(stg + tid * 4),
                               __ATOMIC_RELAXED, __HIP_MEMORY_SCOPE_AGENT);

        // ---- barrier 1 (monotone counter; syncthreads drains vmcnt before arrival) ----
        ++arrive;
        __syncthreads();
        if (tid == 0) {
            __hip_atomic_fetch_add(flag, 1u, __ATOMIC_RELEASE, __HIP_MEMORY_SCOPE_AGENT);
            unsigned int tgt = 8u * arrive;
            while (__hip_atomic_load(flag, __ATOMIC_RELAXED, __HIP_MEMORY_SCOPE_AGENT) < tgt)
                __builtin_amdgcn_s_sleep(1);
        }
        __syncthreads();

        // E: fetch full S -> LDS
        unsigned long long sv =
            __hip_atomic_load(Sg + tid, __ATOMIC_RELAXED, __HIP_MEMORY_SCOPE_AGENT);
        *(unsigned long long*)(sH + uoff) = sv;
        __syncthreads();

        // F: pass 2 partials: rec[r][jj] over i in [q*64, q*64+64)
        {
            float acc[4] = {0.f, 0.f, 0.f, 0.f};
            #pragma unroll
            for (int k = 0; k < 8; ++k) {
                const int i8 = q * 8 + k;
                h8v wv = w2p[i8 * 64 + jj];
                h2v wA = {wv[0], wv[1]}, wB = {wv[2], wv[3]},
                    wC = {wv[4], wv[5]}, wD = {wv[6], wv[7]};
                #pragma unroll
                for (int rr = 0; rr < 4; ++rr) {
                    h8v av = *(const h8v*)(sH + rr * NH + i8 * 8);
                    h2v aA = {av[0], av[1]}, aB = {av[2], av[3]},
                        aC = {av[4], av[5]}, aD = {av[6], av[7]};
                    float a = acc[rr];
                    a = FDOT2(wA, aA, a); a = FDOT2(wB, aB, a);
                    a = FDOT2(wC, aC, a); a = FDOT2(wD, aD, a);
                    acc[rr] = a;
                }
            }
            *(float4*)(zred + (q * 64 + jj) * 4) = make_float4(acc[0], acc[1], acc[2], acc[3]);
        }
        __syncthreads();

        // owner: reduce, pointwise update, store out, stage hy
        if (owner) {
            float rec = 0.f;
            #pragma unroll
            for (int qq = 0; qq < 8; ++qq) rec += zred[(qq * 64 + jj) * 4 + r];
            hz = hz + DT * (iv - rec - hy - hz);
            hy = hy + DT * hz;
            outRow[(size_t)t * NH] = hy;
            stg[r * 64 + jj] = (_Float16)hy;
        }
        __syncthreads();

        if (tid < 64)
            __hip_atomic_store(HYg + m * 64 + tid, *(const unsigned long long*)(stg + tid * 4),
                               __ATOMIC_RELAXED, __HIP_MEMORY_SCOPE_AGENT);

        // ---- barrier 2 ----
        ++arrive;
        __syncthreads();
        if (tid == 0) {
            __hip_atomic_fetch_add(flag, 1u, __ATOMIC_RELEASE, __HIP_MEMORY_SCOPE_AGENT);
            unsigned int tgt = 8u * arrive;
            while (__hip_atomic_load(flag, __ATOMIC_RELAXED, __HIP_MEMORY_SCOPE_AGENT) < tgt)
                __builtin_amdgcn_s_sleep(1);
        }
        __syncthreads();
    }

    // hy_f (concatenated after all_states)
    if (owner)
        out[(size_t)NB * T_STEPS * NH + (size_t)(4 * G + r) * NH + jm + jj] = hy;
}

// ---------- launch ----------
extern "C" void kernel_launch(void* const* d_in, const int* in_sizes, int n_in,
                              void* d_out, int out_size, void* d_ws, size_t ws_size,
                              hipStream_t stream) {
    const float* x    = (const float*)d_in[0];   // [128,1024,64]
    const float* x2h  = (const float*)d_in[1];   // [64,512]
    const float* h2h  = (const float*)d_in[2];   // [512,512]
    const float* bias = (const float*)d_in[3];   // [512]
    float* out = (float*)d_out;

    // ws layout: flags 4 KB | HYx 128 KB | Sx 128 KB
    unsigned int* flags      = (unsigned int*)d_ws;
    unsigned long long* HYx  = (unsigned long long*)((char*)d_ws + 4096);
    unsigned long long* Sx   = (unsigned long long*)((char*)d_ws + 4096 + 131072);

    hipMemsetAsync(d_ws, 0, 4096 + 131072 + 131072, stream);

    i2h_kernel<<<8192, 512, 0, stream>>>(x, x2h, out);

    hipFuncSetAttribute((const void*)recur2,
                        hipFuncAttributeMaxDynamicSharedMemorySize, LDS_BYTES);
    recur2<<<256, 512, LDS_BYTES, stream>>>(h2h, bias, out, HYx, Sx, flags);
}